// Round 6
// baseline (130.057 us; speedup 1.0000x reference)
//
#include <hip/hip_runtime.h>
#include <math.h>

// Problem constants (fixed by setup_inputs): B=4, N=2048, C=32
#define NB 4
#define NA 2048
#define NC 32
#define NATOM (NB * NA)         // 8192
#define IT 256                  // threads per block (pair kernel)
#define UI 2                    // i-atoms per thread (ILP)
#define ITILE (IT * UI)         // 512 i per block
#define NS 64                   // j-splits
#define JT (NA / NS)            // 32 j per block
#define NI (NA / ITILE)         // 4
#define NPAIRBLK (NS * NI * NB) // 1024 blocks = 4096 waves = 16/CU

static constexpr float CONV001 = 3.3207156f;   // 332.07156 * 0.01

// ws layout (floats) — everything used is either fully overwritten each call
// or zeroed by atom_kernel (stream-ordered before pair_kernel):
//   [0, 32768)        Pi[a] = {x,y,z,s_i}  (8192 float4)
//   [32768, 65536)    Pj[a] = {x,y,z,s_j}  (8192 float4)
//   [65536, 65540)    per-batch pair+self accumulators (atomic f32)
//   [65540]           completion counter (unsigned)
//   [65544, 65576)    self partial slots (32; 8 per batch)
#define WS_PI   0
#define WS_PJ   32768
#define WS_ACC  65536
#define WS_CNT  65540
#define WS_SELF 65544

// Pass 1: per-atom scalars -> packed {x,y,z,s} arrays + E_self partials.
// Also zeroes the pair accumulators + counter (visible to pass 2 at the
// dispatch boundary). grid = 32 blocks x 256.
__global__ void __launch_bounds__(256)
atom_kernel(const float* __restrict__ X,
            const float* __restrict__ embs,
            const float* __restrict__ qs,
            const float* __restrict__ born,
            const float* __restrict__ die,
            const float* __restrict__ sf,
            float* __restrict__ ws) {
    if (blockIdx.x == 0 && threadIdx.x < 5)
        ws[WS_ACC + threadIdx.x] = 0.f;   // 4 accumulators + counter

    const int a = blockIdx.x * 256 + threadIdx.x;    // global atom id
    const float4* e4 = (const float4*)(embs + (size_t)a * NC);

    float si = 0.f, sj = 0.f, ad = 0.f, R = 0.f;
    #pragma unroll
    for (int c = 0; c < NC / 4; ++c) {
        float4 ev = e4[c];
        si = fmaf(ev.x, sf[4 * c + 0], fmaf(ev.y, sf[4 * c + 1],
             fmaf(ev.z, sf[4 * c + 2], fmaf(ev.w, sf[4 * c + 3], si))));
        sj = fmaf(ev.x, sf[NC + 4 * c + 0], fmaf(ev.y, sf[NC + 4 * c + 1],
             fmaf(ev.z, sf[NC + 4 * c + 2], fmaf(ev.w, sf[NC + 4 * c + 3], sj))));
        ad = fmaf(ev.x, die[4 * c + 0], fmaf(ev.y, die[4 * c + 1],
             fmaf(ev.z, die[4 * c + 2], fmaf(ev.w, die[4 * c + 3], ad))));
        R  = fmaf(ev.x, born[4 * c + 0], fmaf(ev.y, born[4 * c + 1],
             fmaf(ev.z, born[4 * c + 2], fmaf(ev.w, born[4 * c + 3], R))));
    }
    float x = X[a * 3 + 0];
    float y = X[a * 3 + 1];
    float z = X[a * 3 + 2];
    ((float4*)(ws + WS_PI))[a] = make_float4(x, y, z, si);
    ((float4*)(ws + WS_PJ))[a] = make_float4(x, y, z, sj);

    ad += 1e-6f;
    R  += 1.0f;
    float eself = -(1.0f - __builtin_amdgcn_rcpf(ad)) * qs[a]
                  * __builtin_amdgcn_rcpf(R + 1e-6f);

    #pragma unroll
    for (int off = 32; off > 0; off >>= 1)
        eself += __shfl_down(eself, off, 64);
    __shared__ float wsum[4];
    int lane = threadIdx.x & 63;
    int w = threadIdx.x >> 6;
    if (lane == 0) wsum[w] = eself;
    __syncthreads();
    if (threadIdx.x == 0)
        ws[WS_SELF + blockIdx.x] = wsum[0] + wsum[1] + wsum[2] + wsum[3];
}

// Pass 2: N^2 pair energy + last-block finalize.
__global__ void __launch_bounds__(IT)
pair_kernel(float* __restrict__ ws,
            const float* __restrict__ sf,
            float* __restrict__ out) {
    const int b  = blockIdx.z;
    const int t  = threadIdx.x;
    const int i0 = b * NA + blockIdx.y * ITILE;
    const int j0 = b * NA + blockIdx.x * JT;

    const float4* Pi = (const float4*)(ws + WS_PI);
    const float4* Pj = (const float4*)(ws + WS_PJ);

    __shared__ float4 jd[JT];   // {x, y, z, s_j}
    if (t < JT)
        jd[t] = Pj[j0 + t];

    float4 id[UI];
    #pragma unroll
    for (int u = 0; u < UI; ++u)
        id[u] = Pi[i0 + u * IT + t];
    __syncthreads();

    float acc[UI] = {0.f, 0.f};
    // E_pair ~= rsqrt(d2)*(si+sj) + wd  (wd*N^2 in closed form at finalize)
    #pragma unroll 4
    for (int jj = 0; jj < JT; ++jj) {
        float4 v = jd[jj];
        #pragma unroll
        for (int u = 0; u < UI; ++u) {
            float dx = v.x - id[u].x;
            float dy = v.y - id[u].y;
            float dz = v.z - id[u].z;
            float d2 = fmaf(dx, dx, fmaf(dy, dy, fmaf(dz, dz, 3e-6f)));
            acc[u] = fmaf(__builtin_amdgcn_rsqf(d2), id[u].w + v.w, acc[u]);
        }
    }

    float a = acc[0] + acc[1];
    #pragma unroll
    for (int off = 32; off > 0; off >>= 1)
        a += __shfl_down(a, off, 64);
    __shared__ float wsum[IT / 64];
    int lane = t & 63;
    int w = t >> 6;
    if (lane == 0) wsum[w] = a;
    __syncthreads();

    __shared__ bool amLast;
    if (t == 0) {
        atomicAdd(&ws[WS_ACC + b], wsum[0] + wsum[1] + wsum[2] + wsum[3]);
        __threadfence();
        unsigned old = atomicAdd((unsigned*)&ws[WS_CNT], 1u);
        amLast = (old == NPAIRBLK - 1);
    }
    __syncthreads();

    if (amLast && t < NB) {
        float pair = __hip_atomic_load(&ws[WS_ACC + t], __ATOMIC_RELAXED,
                                       __HIP_MEMORY_SCOPE_AGENT);
        float self = 0.f;
        #pragma unroll
        for (int k = 0; k < 8; ++k)
            self += ws[WS_SELF + t * 8 + k];
        float wd = sf[2 * NC];
        float r = CONV001 * 0.5f * (pair + 2.0f * self
                                    + wd * (float)NA * (float)NA);
        out[t] = isnan(r) ? 1e-6f : r;
    }
}

extern "C" void kernel_launch(void* const* d_in, const int* in_sizes, int n_in,
                              void* d_out, int out_size, void* d_ws, size_t ws_size,
                              hipStream_t stream) {
    const float* X    = (const float*)d_in[0];
    const float* embs = (const float*)d_in[1];
    const float* qs   = (const float*)d_in[2];
    // d_in[3] = paired_mask (unused by reference math)
    const float* born = (const float*)d_in[4];
    const float* die  = (const float*)d_in[5];
    const float* sf   = (const float*)d_in[6];
    float* ws  = (float*)d_ws;
    float* out = (float*)d_out;

    atom_kernel<<<NATOM / 256, 256, 0, stream>>>(X, embs, qs, born, die, sf, ws);
    pair_kernel<<<dim3(NS, NI, NB), IT, 0, stream>>>(ws, sf, out);
}

// Round 7
// 109.046 us; speedup vs baseline: 1.1927x; 1.1927x over previous
//
#include <hip/hip_runtime.h>
#include <math.h>

// Problem constants (fixed by setup_inputs): B=4, N=2048, C=32
#define NB 4
#define NA 2048
#define NC 32
#define NATOM (NB * NA)         // 8192
#define IT 256                  // threads per block (pair kernel)
#define UI 2                    // i-atoms per thread (ILP)
#define ITILE (IT * UI)         // 512 i per block
#define NS 64                   // j-splits
#define JT (NA / NS)            // 32 j per block
#define NI (NA / ITILE)         // 4
// pair grid = (NS, NI, NB) = 1024 blocks = 4096 waves = 16/CU

static constexpr float CONV001 = 3.3207156f;   // 332.07156 * 0.01

// ws layout (floats) — every slot fully overwritten each call (poison-safe):
//   [0, 32768)        Pi[a] = {x,y,z,s_i}  (8192 float4)
//   [32768, 65536)    Pj[a] = {x,y,z,s_j}  (8192 float4)
//   [65536, 66560)    pair partial slots (1024)
//   [66560, 66592)    self partial slots (32; 8 per batch)
// NOTE (R6 lesson): do NOT replace the private-slot scheme with a
// last-block atomic+__threadfence finalize — device-scope fence per block
// across 8 XCDs cost +22 us.
#define WS_PI   0
#define WS_PJ   32768
#define WS_PAIR 65536
#define WS_SELF 66560

// Pass 1: per-atom scalars + packed position/scalar arrays + E_self partials.
__global__ void __launch_bounds__(256)
atom_kernel(const float* __restrict__ X,
            const float* __restrict__ embs,
            const float* __restrict__ qs,
            const float* __restrict__ born,
            const float* __restrict__ die,
            const float* __restrict__ sf,
            float* __restrict__ ws) {
    const int a = blockIdx.x * 256 + threadIdx.x;    // global atom id
    const float4* e4 = (const float4*)(embs + (size_t)a * NC);

    float si = 0.f, sj = 0.f, ad = 0.f, R = 0.f;
    #pragma unroll
    for (int c = 0; c < NC / 4; ++c) {
        float4 ev = e4[c];
        si = fmaf(ev.x, sf[4 * c + 0], fmaf(ev.y, sf[4 * c + 1],
             fmaf(ev.z, sf[4 * c + 2], fmaf(ev.w, sf[4 * c + 3], si))));
        sj = fmaf(ev.x, sf[NC + 4 * c + 0], fmaf(ev.y, sf[NC + 4 * c + 1],
             fmaf(ev.z, sf[NC + 4 * c + 2], fmaf(ev.w, sf[NC + 4 * c + 3], sj))));
        ad = fmaf(ev.x, die[4 * c + 0], fmaf(ev.y, die[4 * c + 1],
             fmaf(ev.z, die[4 * c + 2], fmaf(ev.w, die[4 * c + 3], ad))));
        R  = fmaf(ev.x, born[4 * c + 0], fmaf(ev.y, born[4 * c + 1],
             fmaf(ev.z, born[4 * c + 2], fmaf(ev.w, born[4 * c + 3], R))));
    }
    float x = X[a * 3 + 0];
    float y = X[a * 3 + 1];
    float z = X[a * 3 + 2];
    ((float4*)(ws + WS_PI))[a] = make_float4(x, y, z, si);
    ((float4*)(ws + WS_PJ))[a] = make_float4(x, y, z, sj);

    ad += 1e-6f;
    R  += 1.0f;
    float eself = -(1.0f - __builtin_amdgcn_rcpf(ad)) * qs[a]
                  * __builtin_amdgcn_rcpf(R + 1e-6f);

    // block reduction -> private self slot
    #pragma unroll
    for (int off = 32; off > 0; off >>= 1)
        eself += __shfl_down(eself, off, 64);
    __shared__ float wsum[4];
    int lane = threadIdx.x & 63;
    int w = threadIdx.x >> 6;
    if (lane == 0) wsum[w] = eself;
    __syncthreads();
    if (threadIdx.x == 0)
        ws[WS_SELF + blockIdx.x] = wsum[0] + wsum[1] + wsum[2] + wsum[3];
}

// Pass 2: N^2 pair energy with precomputed packed atom data.
__global__ void __launch_bounds__(IT)
pair_kernel(const float* __restrict__ wsc,
            float* __restrict__ ws) {
    const int b  = blockIdx.z;
    const int t  = threadIdx.x;
    const int i0 = b * NA + blockIdx.y * ITILE;
    const int j0 = b * NA + blockIdx.x * JT;

    const float4* Pi = (const float4*)(wsc + WS_PI);
    const float4* Pj = (const float4*)(wsc + WS_PJ);

    __shared__ float4 jd[JT];   // {x, y, z, s_j}
    if (t < JT)
        jd[t] = Pj[j0 + t];

    float4 id[UI];
    #pragma unroll
    for (int u = 0; u < UI; ++u)
        id[u] = Pi[i0 + u * IT + t];
    __syncthreads();

    float acc[UI] = {0.f, 0.f};
    // E_pair ~= rsqrt(d2)*(si+sj) + wd  (wd*N^2 in closed form at finalize)
    #pragma unroll 4
    for (int jj = 0; jj < JT; ++jj) {
        float4 v = jd[jj];
        #pragma unroll
        for (int u = 0; u < UI; ++u) {
            float dx = v.x - id[u].x;
            float dy = v.y - id[u].y;
            float dz = v.z - id[u].z;
            float d2 = fmaf(dx, dx, fmaf(dy, dy, fmaf(dz, dz, 3e-6f)));
            acc[u] = fmaf(__builtin_amdgcn_rsqf(d2), id[u].w + v.w, acc[u]);
        }
    }

    float a = acc[0] + acc[1];
    #pragma unroll
    for (int off = 32; off > 0; off >>= 1)
        a += __shfl_down(a, off, 64);
    __shared__ float wsum[IT / 64];
    int lane = t & 63;
    int w = t >> 6;
    if (lane == 0) wsum[w] = a;
    __syncthreads();
    if (t == 0) {
        int slot = (b * NI + blockIdx.y) * NS + blockIdx.x;
        ws[WS_PAIR + slot] = wsum[0] + wsum[1] + wsum[2] + wsum[3];
    }
}

// Pass 3: one 1024-thread block; batch b owned by waves 4b..4b+3.
__global__ void __launch_bounds__(1024)
finalize_kernel(const float* __restrict__ ws,
                const float* __restrict__ sf,
                float* __restrict__ out) {
    int t = threadIdx.x;
    float v = ws[WS_PAIR + t];
    #pragma unroll
    for (int off = 32; off > 0; off >>= 1)
        v += __shfl_down(v, off, 64);
    __shared__ float wsum[16];
    if ((t & 63) == 0) wsum[t >> 6] = v;
    __syncthreads();
    if (t < NB) {
        float pair = wsum[4 * t] + wsum[4 * t + 1]
                   + wsum[4 * t + 2] + wsum[4 * t + 3];
        float self = 0.f;
        #pragma unroll
        for (int k = 0; k < 8; ++k)
            self += ws[WS_SELF + t * 8 + k];
        float wd = sf[2 * NC];
        float r = CONV001 * 0.5f * (pair + 2.0f * self
                                    + wd * (float)NA * (float)NA);
        out[t] = isnan(r) ? 1e-6f : r;
    }
}

extern "C" void kernel_launch(void* const* d_in, const int* in_sizes, int n_in,
                              void* d_out, int out_size, void* d_ws, size_t ws_size,
                              hipStream_t stream) {
    const float* X    = (const float*)d_in[0];
    const float* embs = (const float*)d_in[1];
    const float* qs   = (const float*)d_in[2];
    // d_in[3] = paired_mask (unused by reference math)
    const float* born = (const float*)d_in[4];
    const float* die  = (const float*)d_in[5];
    const float* sf   = (const float*)d_in[6];
    float* ws  = (float*)d_ws;
    float* out = (float*)d_out;

    atom_kernel<<<NATOM / 256, 256, 0, stream>>>(X, embs, qs, born, die, sf, ws);
    pair_kernel<<<dim3(NS, NI, NB), IT, 0, stream>>>(ws, ws);
    finalize_kernel<<<1, 1024, 0, stream>>>(ws, sf, out);
}